// Round 13
// baseline (186.097 us; speedup 1.0000x reference)
//
#include <hip/hip_runtime.h>
#include <hip/hip_bf16.h>

using bf16 = __hip_bfloat16;
typedef __attribute__((ext_vector_type(8))) short short8;   // 8 bf16 = 4 VGPRs (MFMA A/B frag)
typedef __attribute__((ext_vector_type(4))) float floatx4;  // MFMA C/D frag

#define B_  2
#define T_  2048
#define C_  1024
#define H_  16
#define HD_ 64
#define BT_ (B_*T_)
#define NX_ ((size_t)BT_*C_)   /* 4M elems */
#define NW_ ((size_t)C_*C_)    /* 1M elems */
#define PSTR2 40               /* Ps chunk row stride (elems): 80B; writes 2-way (free) */
#define KSCQ 0.1803368801f     /* (1/sqrt(64)) * log2(e), folded into Q at qkv epilogue */

// async global->LDS, 16B per lane. LDS dest is wave-uniform base; lane i lands at base + i*16B.
__device__ __forceinline__ void gl2lds16(const bf16* g, bf16* l) {
    __builtin_amdgcn_global_load_lds((const __attribute__((address_space(1))) unsigned int*)g,
                                     (__attribute__((address_space(3))) unsigned int*)l,
                                     16, 0, 0);
}

// ---------------------------------------------------------------------------
// Kernel 0: f32 -> bf16 conversion for x and the 4 weight matrices.
// ---------------------------------------------------------------------------
__global__ __launch_bounds__(256) void cvt_f32_bf16(
    const float* __restrict__ x,
    const float* __restrict__ Wq, const float* __restrict__ Wk,
    const float* __restrict__ Wv, const float* __restrict__ Wp,
    bf16* __restrict__ xb, bf16* __restrict__ wqb, bf16* __restrict__ wkb,
    bf16* __restrict__ wvb, bf16* __restrict__ wpb)
{
    size_t i4 = ((size_t)blockIdx.x * 256 + threadIdx.x) * 4;
    const float* src; bf16* dst; size_t off;
    if (i4 < NX_) { src = x; dst = xb; off = i4; }
    else {
        size_t j = i4 - NX_;
        int r = (int)(j >> 20);
        off = j & (NW_ - 1);
        src = (r==0) ? Wq : (r==1) ? Wk : (r==2) ? Wv : Wp;
        dst = (r==0) ? wqb : (r==1) ? wkb : (r==2) ? wvb : wpb;
    }
    float4 v = *(const float4*)(src + off);
    union { bf16 h[4]; uint2 u; } o;
    o.h[0] = __float2bfloat16(v.x); o.h[1] = __float2bfloat16(v.y);
    o.h[2] = __float2bfloat16(v.z); o.h[3] = __float2bfloat16(v.w);
    *(uint2*)(dst + off) = o.u;
}

// ---------------------------------------------------------------------------
// Kernel A: fused QKV projection.  y = x @ W^T + b for W in {Wq,Wk,Wv}.
// Grid (32 mtiles, 24 ntiles). ntile/8 selects the weight. 128x128 tile, BK=32
// (BK=64 measured +3us slower end-to-end — reverted, R11).
// Q stored PRE-SCALED by KSCQ; Q,K stored [B,T,C]; V stored [B,H,HD,T].
// ---------------------------------------------------------------------------
__global__ __launch_bounds__(256) void qkv_gemm(
    const bf16* __restrict__ x,
    const bf16* __restrict__ Wq, const float* __restrict__ bq,
    const bf16* __restrict__ Wk, const float* __restrict__ bk,
    const bf16* __restrict__ Wv, const float* __restrict__ bv,
    bf16* __restrict__ qo, bf16* __restrict__ ko, bf16* __restrict__ vt)
{
    __shared__ __align__(16) bf16 As[128*32];
    __shared__ __align__(16) bf16 Bs[128*32];

    const int tid  = threadIdx.x;
    const int w    = tid >> 6, lane = tid & 63;
    const int g    = lane >> 4, c16 = lane & 15;
    const int wr   = w >> 1,    wc  = w & 1;
    const int mtile = blockIdx.x, ntile = blockIdx.y;
    const int wsel  = ntile >> 3;                 // 0=Q 1=K 2=V (uniform per block)
    const bf16*  W    = (wsel==0) ? Wq : (wsel==1 ? Wk : Wv);
    const float* bias = (wsel==0) ? bq : (wsel==1 ? bk : bv);
    const float oscale = (wsel==0) ? KSCQ : 1.0f;
    const int nbase  = (ntile & 7) * 128;

    const bf16* ag = x + (size_t)(mtile*128)*C_;
    const bf16* bg = W + (size_t)nbase*C_;

    floatx4 acc[4][4] = {};

    for (int k0 = 0; k0 < C_; k0 += 32) {
        #pragma unroll
        for (int p = 0; p < 2; ++p) {
            int cb = p*256 + w*64;        // wave-uniform chunk base
            int c  = cb + lane;           // this lane's chunk: row=c>>2, colgrp=c&3
            gl2lds16(ag + (size_t)(c>>2)*C_ + k0 + (c&3)*8, As + cb*8);
            gl2lds16(bg + (size_t)(c>>2)*C_ + k0 + (c&3)*8, Bs + cb*8);
        }
        __syncthreads();

        short8 af[4], bfr[4];
        #pragma unroll
        for (int i = 0; i < 4; ++i)
            af[i] = *(const short8*)(As + (wr*64 + i*16 + c16)*32 + g*8);
        #pragma unroll
        for (int j = 0; j < 4; ++j)
            bfr[j] = *(const short8*)(Bs + (wc*64 + j*16 + c16)*32 + g*8);
        #pragma unroll
        for (int i = 0; i < 4; ++i)
            #pragma unroll
            for (int j = 0; j < 4; ++j)
                acc[i][j] = __builtin_amdgcn_mfma_f32_16x16x32_bf16(af[i], bfr[j], acc[i][j], 0, 0, 0);
        __syncthreads();
    }

    // Epilogue. C/D layout: row=(lane>>4)*4+reg, col=lane&15.
    #pragma unroll
    for (int i = 0; i < 4; ++i) {
        int m0 = mtile*128 + wr*64 + i*16 + g*4;     // 4 consecutive rows m0..m0+3
        #pragma unroll
        for (int j = 0; j < 4; ++j) {
            int n = nbase + wc*64 + j*16 + c16;      // output channel 0..1023
            float bvf = bias[n];
            if (wsel == 2) {
                // V transposed: vt[b][h][hd][t]; 4 regs = 4 consecutive t -> one 8B store
                int bb = m0 >> 11, t0 = m0 & (T_-1);
                int hh = n >> 6,  hd = n & 63;
                union { bf16 hv[4]; uint2 u; } tmp;
                #pragma unroll
                for (int r = 0; r < 4; ++r) tmp.hv[r] = __float2bfloat16(acc[i][j][r] + bvf);
                *(uint2*)(vt + ((size_t)((bb*H_ + hh)*64 + hd))*T_ + t0) = tmp.u;
            } else {
                bf16* dst = (wsel==0) ? qo : ko;
                #pragma unroll
                for (int r = 0; r < 4; ++r)
                    dst[(size_t)(m0+r)*C_ + n] = __float2bfloat16((acc[i][j][r] + bvf) * oscale);
            }
        }
    }
}

// ---------------------------------------------------------------------------
// Kernel B v17b: causal flash attention — 32q x 32key wave tiles.
// (v17 failed correctness: combine-scratch offset had a stray *2 — donor slot
// d=2 at float offset 5120 overran Ks's 4096 floats into Vs, colliding with
// donors d=3/4. Fixed: slots at (d%3)*1280 floats, max 3840 <= 4096.)
// v16 ledger (44.4us): MFMA 17% + VALU 27% + ~55% LDS-pipe/barrier. LDS reads
// were 18 b128/wave/iter (8 K + 8 V + 2 Ps). Re-shape: wave (wq2,kh4) =
// (w&1, w>>1) owns 32 q-rows (2 qh of 16) x 32 keys (quarter) — same MFMA
// count, but each kb/vb read feeds BOTH qh -> K/V reads 16 -> 8 per iter
// (total 10 b128, -44% on the binding pipe). exp count, Ps traffic, MFMA,
// staging all unchanged. Unlike v14 (spilled): both qh always active, no
// conditional paths; live state ~110 VGPR < 128 cap @ 4 waves/SIMD.
// 4-way key-split partials stay additive (no-max softmax): combine per
// qh-round via dead Ks/Vs scratch (3 donor slots per 16KB buffer).
// Keeps: causal fold {p,31-p} (17 uniform iters), single-buffer staging +
// 2 barriers/tile, raw v_exp_f32, T5 setprio, XCD swizzle, ones-MFMA l.
// ---------------------------------------------------------------------------
__global__ __launch_bounds__(512, 4) void attn(
    const bf16* __restrict__ q, const bf16* __restrict__ k,
    const bf16* __restrict__ vt, bf16* __restrict__ y)
{
    __shared__ __align__(16) bf16 Ks[16*512];          // 16KB: frag f = ct_glob*2+kg
    __shared__ __align__(16) bf16 Vs[16*512];          // 16KB: frag f = ksg*4+nt
    __shared__ __align__(16) bf16 Ps[8][2][16*PSTR2];  // 20KB: per-wave chunk x qh

    const int tid = threadIdx.x, w = tid >> 6, lane = tid & 63;
    const int g = lane >> 4, c16 = lane & 15;
    const int wq2 = w & 1;                        // q half (32 rows) within q-tile
    const int kh4 = w >> 1;                       // key quarter (32 keys) 0..3

    // XCD swizzle: bh = hi*8 + (blockIdx & 7); same-bh blocks land on one XCD
    const int xcd = blockIdx.x & 7;
    const int j   = blockIdx.x >> 3;              // 0..63
    const int p   = j & 15;                       // fold pair {p, 31-p}
    const int bh  = (j >> 4) * 8 + xcd;           // 0..31
    const int b = bh >> 4, h = bh & 15;

    const bf16* kbase = k  + ((size_t)(b*T_))*C_ + h*64;
    const bf16* vbase = vt + ((size_t)(b*H_ + h))*64*T_;

    const short ONEB = 0x3F80;                    // bf16 1.0
    const short8 ones = {ONEB,ONEB,ONEB,ONEB,ONEB,ONEB,ONEB,ONEB};

    for (int ph = 0; ph < 2; ++ph) {
        const int qt = ph ? 31 - p : p;
        const int nit = (qt + 2) >> 1;            // # 128-key tiles (causal)
        const int qrow0 = qt*64 + wq2*32;         // wave's first q row
        int qglob[2]; qglob[0] = qrow0 + c16; qglob[1] = qrow0 + 16 + c16;

        // Q frags (B-operand): [q=c16][d=g*8+j], pre-scaled by KSCQ; 2 qh
        short8 aq[2][2];   // [qh][kg]
        #pragma unroll
        for (int qh = 0; qh < 2; ++qh)
            #pragma unroll
            for (int kg = 0; kg < 2; ++kg)
                aq[qh][kg] = *(const short8*)(q + ((size_t)(b*T_ + qglob[qh]))*C_ + h*64 + kg*32 + g*8);

        floatx4 accO[4][2] = {};                  // [nt][qh]
        floatx4 lacc[2] = {};                     // l in accO row layout

        for (int kt = 0; kt < nit; ++kt) {
            // stage 16 K + 16 V frags; wave w stages frags {2w, 2w+1} of each
            #pragma unroll
            for (int e = 0; e < 2; ++e) {
                int f = w*2 + e;
                gl2lds16(kbase + (size_t)(kt*128 + (f>>1)*16 + c16)*C_ + (f&1)*32 + g*8, Ks + f*512);
                gl2lds16(vbase + (size_t)((f&3)*16 + c16)*T_ + kt*128 + (f>>2)*32 + g*8, Vs + f*512);
            }
            __syncthreads();

            // S^T = K Q^T over this wave's 32 keys x both qh: kb shared across qh
            floatx4 s[2][2];                      // [qh][ct]
            __builtin_amdgcn_s_setprio(1);
            #pragma unroll
            for (int ct = 0; ct < 2; ++ct) {
                int ce = kh4*2 + ct;              // global 16-key group 0..7
                short8 kb0 = *(const short8*)(Ks + (ce*2+0)*512 + lane*8);
                short8 kb1 = *(const short8*)(Ks + (ce*2+1)*512 + lane*8);
                #pragma unroll
                for (int qh = 0; qh < 2; ++qh) {
                    floatx4 a = {0.f, 0.f, 0.f, 0.f};
                    a = __builtin_amdgcn_mfma_f32_16x16x32_bf16(kb0, aq[qh][0], a, 0, 0, 0);
                    a = __builtin_amdgcn_mfma_f32_16x16x32_bf16(kb1, aq[qh][1], a, 0, 0, 0);
                    s[qh][ct] = a;
                }
            }
            __builtin_amdgcn_s_setprio(0);

            if (kt == nit-1) {   // causal mask: key > q  (all operands lane-local)
                #pragma unroll
                for (int qh = 0; qh < 2; ++qh)
                    #pragma unroll
                    for (int ct = 0; ct < 2; ++ct)
                        #pragma unroll
                        for (int r = 0; r < 4; ++r) {
                            int key = kt*128 + kh4*32 + ct*16 + g*4 + r;
                            if (key > qglob[qh]) s[qh][ct][r] = -1e30f;
                        }
            }

            // exp+pack both qh 32-key chunks; read back as A-frags; accumulate
            // l (ones-MFMA) and O (4 nt MFMA, vb shared across qh).
            #pragma unroll
            for (int qh = 0; qh < 2; ++qh) {
                #pragma unroll
                for (int ct = 0; ct < 2; ++ct) {
                    float p0 = __builtin_amdgcn_exp2f(s[qh][ct][0]);
                    float p1 = __builtin_amdgcn_exp2f(s[qh][ct][1]);
                    float p2 = __builtin_amdgcn_exp2f(s[qh][ct][2]);
                    float p3 = __builtin_amdgcn_exp2f(s[qh][ct][3]);
                    union { __hip_bfloat162 h2[2]; uint2 u; } pk;
                    pk.h2[0] = __float22bfloat162_rn(float2{p0, p1});
                    pk.h2[1] = __float22bfloat162_rn(float2{p2, p3});
                    *(uint2*)(Ps[w][qh] + c16*PSTR2 + ct*16 + g*4) = pk.u;
                }
            }
            short8 pa0 = *(const short8*)(Ps[w][0] + c16*PSTR2 + g*8);
            short8 pa1 = *(const short8*)(Ps[w][1] + c16*PSTR2 + g*8);
            __builtin_amdgcn_s_setprio(1);
            lacc[0] = __builtin_amdgcn_mfma_f32_16x16x32_bf16(pa0, ones, lacc[0], 0, 0, 0);
            lacc[1] = __builtin_amdgcn_mfma_f32_16x16x32_bf16(pa1, ones, lacc[1], 0, 0, 0);
            #pragma unroll
            for (int nt = 0; nt < 4; ++nt) {
                short8 vb = *(const short8*)(Vs + (kh4*4 + nt)*512 + lane*8);
                accO[nt][0] = __builtin_amdgcn_mfma_f32_16x16x32_bf16(pa0, vb, accO[nt][0], 0, 0, 0);
                accO[nt][1] = __builtin_amdgcn_mfma_f32_16x16x32_bf16(pa1, vb, accO[nt][1], 0, 0, 0);
            }
            __builtin_amdgcn_s_setprio(0);
            __syncthreads();
        }

        // combine 4-way key-split partials (waves with same wq2, kh4 = 0..3
        // share q-rows, disjoint keys; no-max softmax => additive), per qh
        // round through dead Ks/Vs scratch. Donors: w>=2 (d = w-2 in 0..5),
        // slot = (d%3)*1280 floats in Ks (d<3) or Vs (d>=3); each slot
        // 64 lanes x 20 floats = 1280 -> 3 slots = 3840 <= 4096 floats/buffer.
        #pragma unroll
        for (int qh = 0; qh < 2; ++qh) {
            if (w >= 2) {
                int d = w - 2;                    // 0..5
                float* dstf = ((d < 3) ? (float*)Ks : (float*)Vs) + (d % 3)*1280 + lane*20;
                #pragma unroll
                for (int nt = 0; nt < 4; ++nt) *(floatx4*)(dstf + nt*4) = accO[nt][qh];
                *(floatx4*)(dstf + 16) = lacc[qh];
            }
            __syncthreads();
            if (w < 2) {
                #pragma unroll
                for (int kq = 1; kq < 4; ++kq) {
                    int dw = kq*2 + wq2 - 2;      // donor slot index: 0..5
                    const float* srcf = ((dw < 3) ? (const float*)Ks : (const float*)Vs) + (dw % 3)*1280 + lane*20;
                    #pragma unroll
                    for (int nt = 0; nt < 4; ++nt) {
                        floatx4 o = *(const floatx4*)(srcf + nt*4);
                        #pragma unroll
                        for (int r = 0; r < 4; ++r) accO[nt][qh][r] += o[r];
                    }
                    floatx4 lo = *(const floatx4*)(srcf + 16);
                    #pragma unroll
                    for (int r = 0; r < 4; ++r) lacc[qh][r] += lo[r];
                }
                // epilogue qh: y = O * (1/l); l in accO row layout -> no shuffles
                float ir[4];
                #pragma unroll
                for (int r = 0; r < 4; ++r) ir[r] = __builtin_amdgcn_rcpf(lacc[qh][r]);
                #pragma unroll
                for (int nt = 0; nt < 4; ++nt)
                    #pragma unroll
                    for (int r = 0; r < 4; ++r) {
                        int row = qrow0 + qh*16 + g*4 + r;
                        float o = accO[nt][qh][r] * ir[r];
                        y[((size_t)(b*T_ + row))*C_ + h*64 + nt*16 + c16] = __float2bfloat16(o);
                    }
            }
            __syncthreads();   // scratch free before next qh round / next phase
        }
    }
}

// ---------------------------------------------------------------------------
// Kernel C: output projection. out = y_att @ Wp^T + bp (f32 output).
// 64x128 tiles, grid (64, 8) = 512 blocks -> 2 blocks/CU. 4 waves span N.
// ---------------------------------------------------------------------------
__global__ __launch_bounds__(256) void proj_gemm(
    const bf16* __restrict__ yin, const bf16* __restrict__ Wp, const float* __restrict__ bp,
    float* __restrict__ out)
{
    __shared__ __align__(16) bf16 As[64*32];    // 4KB
    __shared__ __align__(16) bf16 Bs[128*32];   // 8KB

    const int tid = threadIdx.x;
    const int w = tid >> 6, lane = tid & 63;
    const int g = lane >> 4, c16 = lane & 15;
    const int mtile = blockIdx.x, ntile = blockIdx.y;
    const int nbase = ntile * 128;

    const bf16* ag = yin + (size_t)(mtile*64)*C_;
    const bf16* bg = Wp  + (size_t)nbase*C_;

    floatx4 acc[4][2] = {};

    for (int k0 = 0; k0 < C_; k0 += 32) {
        // As: 64x32 = 4 chunks; wave w stages chunk w (rows w*16..w*16+15)
        gl2lds16(ag + (size_t)(w*16 + (lane>>2))*C_ + k0 + (lane&3)*8, As + w*512);
        // Bs: 128x32 = 8 chunks; wave w stages chunks {w, w+4}
        #pragma unroll
        for (int p = 0; p < 2; ++p) {
            int cb = p*256 + w*64;
            int c  = cb + lane;
            gl2lds16(bg + (size_t)(c>>2)*C_ + k0 + (c&3)*8, Bs + cb*8);
        }
        __syncthreads();

        short8 af[4], bfr[2];
        #pragma unroll
        for (int i = 0; i < 4; ++i)
            af[i] = *(const short8*)(As + (i*16 + c16)*32 + g*8);
        #pragma unroll
        for (int j = 0; j < 2; ++j)
            bfr[j] = *(const short8*)(Bs + (w*32 + j*16 + c16)*32 + g*8);
        #pragma unroll
        for (int i = 0; i < 4; ++i)
            #pragma unroll
            for (int j = 0; j < 2; ++j)
                acc[i][j] = __builtin_amdgcn_mfma_f32_16x16x32_bf16(af[i], bfr[j], acc[i][j], 0, 0, 0);
        __syncthreads();
    }

    #pragma unroll
    for (int i = 0; i < 4; ++i) {
        int m0 = mtile*64 + i*16 + g*4;
        #pragma unroll
        for (int j = 0; j < 2; ++j) {
            int n = nbase + w*32 + j*16 + c16;
            float bvf = bp[n];
            #pragma unroll
            for (int r = 0; r < 4; ++r)
                out[(size_t)(m0+r)*C_ + n] = acc[i][j][r] + bvf;
        }
    }
}

extern "C" void kernel_launch(void* const* d_in, const int* in_sizes, int n_in,
                              void* d_out, int out_size, void* d_ws, size_t ws_size,
                              hipStream_t stream) {
    const float* x  = (const float*)d_in[0];
    const float* Wq = (const float*)d_in[1];
    const float* bq = (const float*)d_in[2];
    const float* Wk = (const float*)d_in[3];
    const float* bk = (const float*)d_in[4];
    const float* Wv = (const float*)d_in[5];
    const float* bv = (const float*)d_in[6];
    const float* Wp = (const float*)d_in[7];
    const float* bp = (const float*)d_in[8];

    // workspace layout (bf16 elements)
    bf16* xb  = (bf16*)d_ws;          // 4M
    bf16* wqb = xb  + NX_;            // 1M
    bf16* wkb = wqb + NW_;            // 1M
    bf16* wvb = wkb + NW_;            // 1M
    bf16* wpb = wvb + NW_;            // 1M
    bf16* qw  = wpb + NW_;            // 4M
    bf16* kw  = qw  + NX_;            // 4M
    bf16* vt  = kw  + NX_;            // 4M
    bf16* yw  = vt  + NX_;            // 4M  -> total 24M bf16 = 48 MB

    const int cvt_blocks = (int)((NX_ + 4*NW_) / (4*256));   // 8192
    cvt_f32_bf16<<<cvt_blocks, 256, 0, stream>>>(x, Wq, Wk, Wv, Wp, xb, wqb, wkb, wvb, wpb);
    qkv_gemm<<<dim3(32, 24), 256, 0, stream>>>(xb, wqb, bq, wkb, bk, wvb, bv, qw, kw, vt);
    attn    <<<512, 512, 0, stream>>>(qw, kw, vt, yw);
    proj_gemm<<<dim3(64, 8), 256, 0, stream>>>(yw, wpb, bp, (float*)d_out);
}